// Round 1
// baseline (8714.989 us; speedup 1.0000x reference)
//
#include <hip/hip_runtime.h>

#define NVAR 1000000
#define NCON 500000
#define HFE 10
#define NPART 2048

// ---------------- degree count ----------------
__global__ __launch_bounds__(256) void k_degree(const int* __restrict__ src,
                                                const int* __restrict__ dst,
                                                unsigned int* __restrict__ deg_var,
                                                unsigned int* __restrict__ deg_con,
                                                int ne) {
    int e = blockIdx.x * blockDim.x + threadIdx.x;
    if (e < ne) {
        atomicAdd(&deg_var[src[e]], 1u);
        atomicAdd(&deg_con[dst[e]], 1u);
    }
}

// ---------------- var embedding, prescaled by rsqrt(deg) ----------------
__global__ __launch_bounds__(256) void k_xvar(const float* __restrict__ var_c,
                                              const float* __restrict__ var_x,
                                              const unsigned int* __restrict__ deg_var,
                                              const float* __restrict__ Wv,
                                              const float* __restrict__ bv,
                                              float* __restrict__ Xs, int n) {
    int i = blockIdx.x * blockDim.x + threadIdx.x;
    if (i >= n) return;
    float c = var_c[i], x = var_x[i];
    unsigned d = deg_var[i];
    float rs = rsqrtf(fmaxf((float)d, 1.0f));
    float o[HFE];
#pragma unroll
    for (int j = 0; j < HFE; j++) {
        float t = fmaf(c, Wv[j], fmaf(x, Wv[HFE + j], bv[j]));
        o[j] = fmaxf(t, 0.0f) * rs;
    }
    float2* dst2 = (float2*)(Xs + (size_t)i * HFE);
#pragma unroll
    for (int j = 0; j < 5; j++) dst2[j] = make_float2(o[2 * j], o[2 * j + 1]);
}

// ---------------- edge scatter: agg[sidx] += w * feat[gidx] ----------------
__global__ __launch_bounds__(256) void k_scatter(const int* __restrict__ gidx,
                                                 const int* __restrict__ sidx,
                                                 const float* __restrict__ w,
                                                 const float* __restrict__ feat,
                                                 float* __restrict__ agg, int ne) {
    int e = blockIdx.x * blockDim.x + threadIdx.x;
    if (e >= ne) return;
    int g = gidx[e];
    int s = sidx[e];
    float we = w[e];
    const float2* f = (const float2*)(feat + (size_t)g * HFE);
    float* a = agg + (size_t)s * HFE;
#pragma unroll
    for (int j = 0; j < 5; j++) {
        float2 v = f[j];
        unsafeAtomicAdd(&a[2 * j], we * v.x);
        unsafeAtomicAdd(&a[2 * j + 1], we * v.y);
    }
}

// ---------------- con update: hs = relu((agg*rs)@W2+b2) * rs ----------------
__global__ __launch_bounds__(256) void k_hcon(const float* __restrict__ agg,
                                              const unsigned int* __restrict__ deg_con,
                                              const float* __restrict__ W2,
                                              const float* __restrict__ b2,
                                              float* __restrict__ hs, int n) {
    __shared__ float sW[HFE * HFE], sb[HFE];
    for (int t = threadIdx.x; t < HFE * HFE; t += blockDim.x) sW[t] = W2[t];
    if (threadIdx.x < HFE) sb[threadIdx.x] = b2[threadIdx.x];
    __syncthreads();
    int i = blockIdx.x * blockDim.x + threadIdx.x;
    if (i >= n) return;
    unsigned d = deg_con[i];
    float rs = rsqrtf(fmaxf((float)d, 1.0f));
    float a[HFE];
    const float2* srow = (const float2*)(agg + (size_t)i * HFE);
#pragma unroll
    for (int j = 0; j < 5; j++) {
        float2 v = srow[j];
        a[2 * j] = v.x * rs;
        a[2 * j + 1] = v.y * rs;
    }
    float o[HFE];
#pragma unroll
    for (int k = 0; k < HFE; k++) {
        float t = sb[k];
#pragma unroll
        for (int j = 0; j < HFE; j++) t = fmaf(a[j], sW[j * HFE + k], t);
        o[k] = fmaxf(t, 0.0f) * rs;   // relu, then prescale for conv2
    }
    float2* dst2 = (float2*)(hs + (size_t)i * HFE);
#pragma unroll
    for (int j = 0; j < 5; j++) dst2[j] = make_float2(o[2 * j], o[2 * j + 1]);
}

// ---------------- final: var update + MLP + partial mean ----------------
__global__ __launch_bounds__(256) void k_final(const float* __restrict__ agg,
                                               const unsigned int* __restrict__ deg_var,
                                               const float* __restrict__ W2,
                                               const float* __restrict__ b2,
                                               const float* __restrict__ Wo1,
                                               const float* __restrict__ bo1,
                                               const float* __restrict__ Wo2,
                                               const float* __restrict__ bo2,
                                               const float* __restrict__ Wo3,
                                               const float* __restrict__ bo3,
                                               double* __restrict__ partials, int n) {
    __shared__ float sW2[100], sb2[10], sWo1[100], sbo1[10], sWo2[100], sbo2[10], sWo3[10], sbo3;
    for (int t = threadIdx.x; t < 100; t += blockDim.x) {
        sW2[t] = W2[t]; sWo1[t] = Wo1[t]; sWo2[t] = Wo2[t];
    }
    if (threadIdx.x < 10) {
        sb2[threadIdx.x] = b2[threadIdx.x];
        sbo1[threadIdx.x] = bo1[threadIdx.x];
        sbo2[threadIdx.x] = bo2[threadIdx.x];
        sWo3[threadIdx.x] = Wo3[threadIdx.x];
    }
    if (threadIdx.x == 0) sbo3 = bo3[0];
    __syncthreads();

    double acc = 0.0;
    for (int i = blockIdx.x * blockDim.x + threadIdx.x; i < n; i += gridDim.x * blockDim.x) {
        unsigned d = deg_var[i];
        float rs = rsqrtf(fmaxf((float)d, 1.0f));
        float a[10], h[10], z[10];
        const float2* srow = (const float2*)(agg + (size_t)i * 10);
#pragma unroll
        for (int j = 0; j < 5; j++) {
            float2 v = srow[j];
            a[2 * j] = v.x * rs;
            a[2 * j + 1] = v.y * rs;
        }
#pragma unroll
        for (int k = 0; k < 10; k++) {
            float t = sb2[k];
#pragma unroll
            for (int j = 0; j < 10; j++) t = fmaf(a[j], sW2[j * 10 + k], t);
            h[k] = fmaxf(t, 0.0f);
        }
#pragma unroll
        for (int k = 0; k < 10; k++) {
            float t = sbo1[k];
#pragma unroll
            for (int j = 0; j < 10; j++) t = fmaf(h[j], sWo1[j * 10 + k], t);
            z[k] = fmaxf(t, 0.0f);
        }
        float t3 = sbo3;
#pragma unroll
        for (int k = 0; k < 10; k++) {
            float t = sbo2[k];
#pragma unroll
            for (int j = 0; j < 10; j++) t = fmaf(z[j], sWo2[j * 10 + k], t);
            t = fmaxf(t, 0.0f);
            t3 = fmaf(t, sWo3[k], t3);
        }
        acc += (double)t3;
    }

    __shared__ double red[256];
    red[threadIdx.x] = acc;
    __syncthreads();
    for (int off = blockDim.x / 2; off > 0; off >>= 1) {
        if (threadIdx.x < off) red[threadIdx.x] += red[threadIdx.x + off];
        __syncthreads();
    }
    if (threadIdx.x == 0) partials[blockIdx.x] = red[0];
}

__global__ __launch_bounds__(256) void k_out(const double* __restrict__ partials, int np,
                                             float* __restrict__ out) {
    __shared__ double red[256];
    double a = 0.0;
    for (int i = threadIdx.x; i < np; i += blockDim.x) a += partials[i];
    red[threadIdx.x] = a;
    __syncthreads();
    for (int off = 128; off > 0; off >>= 1) {
        if (threadIdx.x < off) red[threadIdx.x] += red[threadIdx.x + off];
        __syncthreads();
    }
    if (threadIdx.x == 0) out[0] = (float)(red[0] / (double)NVAR);
}

extern "C" void kernel_launch(void* const* d_in, const int* in_sizes, int n_in,
                              void* d_out, int out_size, void* d_ws, size_t ws_size,
                              hipStream_t stream) {
    const float* var_c  = (const float*)d_in[0];
    const float* var_x  = (const float*)d_in[1];
    // d_in[2] = con_b : unused (X_con is dead in the reference)
    const int*   e_src  = (const int*)d_in[3];
    const int*   e_dst  = (const int*)d_in[4];
    const float* e_w    = (const float*)d_in[5];
    const float* Wv     = (const float*)d_in[6];
    const float* bv     = (const float*)d_in[7];
    // d_in[8..11] = Wc, bc, W1, b1 : unused by the reference math
    const float* W2     = (const float*)d_in[12];
    const float* b2     = (const float*)d_in[13];
    const float* Wo1    = (const float*)d_in[14];
    const float* bo1    = (const float*)d_in[15];
    const float* Wo2    = (const float*)d_in[16];
    const float* bo2    = (const float*)d_in[17];
    const float* Wo3    = (const float*)d_in[18];
    const float* bo3    = (const float*)d_in[19];
    float* out = (float*)d_out;
    const int ne = in_sizes[3];

    // ---- workspace layout (all 256B-aligned) ----
    char* ws = (char*)d_ws;
    size_t off = 0;
    auto walloc = [&](size_t bytes) {
        void* p = ws + off;
        off = (off + bytes + 255) & ~(size_t)255;
        return p;
    };
    float*        Xs       = (float*)walloc((size_t)NVAR * HFE * 4);  // 40 MB
    float*        agg_con  = (float*)walloc((size_t)NCON * HFE * 4);  // 20 MB
    float*        hs_con   = (float*)walloc((size_t)NCON * HFE * 4);  // 20 MB
    float*        agg_var  = (float*)walloc((size_t)NVAR * HFE * 4);  // 40 MB
    unsigned int* deg_var  = (unsigned int*)walloc((size_t)NVAR * 4); //  4 MB
    unsigned int* deg_con  = (unsigned int*)walloc((size_t)NCON * 4); //  2 MB
    double*       partials = (double*)walloc((size_t)NPART * 8);
    (void)ws_size; (void)n_in; (void)out_size;

    // ---- zero accumulators (deg_var & deg_con are adjacent) ----
    hipMemsetAsync(agg_con, 0, (size_t)NCON * HFE * 4, stream);
    hipMemsetAsync(agg_var, 0, (size_t)NVAR * HFE * 4, stream);
    hipMemsetAsync(deg_var, 0, (size_t)NVAR * 4 + (size_t)NCON * 4, stream);

    const int B = 256;
    // degrees
    k_degree<<<(ne + B - 1) / B, B, 0, stream>>>(e_src, e_dst, deg_var, deg_con, ne);
    // var embedding (prescaled)
    k_xvar<<<(NVAR + B - 1) / B, B, 0, stream>>>(var_c, var_x, deg_var, Wv, bv, Xs, NVAR);
    // conv1: var -> con
    k_scatter<<<(ne + B - 1) / B, B, 0, stream>>>(e_src, e_dst, e_w, Xs, agg_con, ne);
    // con dense layer + prescale for conv2
    k_hcon<<<(NCON + B - 1) / B, B, 0, stream>>>(agg_con, deg_con, W2, b2, hs_con, NCON);
    // conv2: con -> var
    k_scatter<<<(ne + B - 1) / B, B, 0, stream>>>(e_dst, e_src, e_w, hs_con, agg_var, ne);
    // var dense layer + output MLP + partial sums
    k_final<<<NPART, B, 0, stream>>>(agg_var, deg_var, W2, b2, Wo1, bo1, Wo2, bo2,
                                     Wo3, bo3, partials, NVAR);
    // final mean
    k_out<<<1, B, 0, stream>>>(partials, NPART, out);
}

// Round 2
// 2454.747 us; speedup vs baseline: 3.5503x; 3.5503x over previous
//
#include <hip/hip_runtime.h>

#define NVAR 1000000
#define NCON 500000
#define HFE 10

// ---------------- degree count (int atomics) ----------------
__global__ __launch_bounds__(256) void k_degree(const int* __restrict__ src,
                                                const int* __restrict__ dst,
                                                unsigned int* __restrict__ deg_var,
                                                unsigned int* __restrict__ deg_con,
                                                int ne) {
    int e = blockIdx.x * blockDim.x + threadIdx.x;
    if (e < ne) {
        atomicAdd(&deg_var[src[e]], 1u);
        atomicAdd(&deg_con[dst[e]], 1u);
    }
}

// ---------------- exclusive scan, 1024 elements / block ----------------
__global__ __launch_bounds__(256) void k_scan_blocks(const unsigned int* __restrict__ in,
                                                     unsigned int* __restrict__ out,
                                                     unsigned int* __restrict__ bsum,
                                                     int n) {
    __shared__ unsigned int sT[256];
    int base = blockIdx.x * 1024 + threadIdx.x * 4;
    unsigned int v0 = 0, v1 = 0, v2 = 0, v3 = 0;
    if (base + 3 < n) {
        uint4 u = *(const uint4*)(in + base);
        v0 = u.x; v1 = u.y; v2 = u.z; v3 = u.w;
    } else {
        if (base     < n) v0 = in[base];
        if (base + 1 < n) v1 = in[base + 1];
        if (base + 2 < n) v2 = in[base + 2];
        if (base + 3 < n) v3 = in[base + 3];
    }
    sT[threadIdx.x] = v0 + v1 + v2 + v3;
    __syncthreads();
    for (int d = 1; d < 256; d <<= 1) {
        unsigned int add = (threadIdx.x >= (unsigned)d) ? sT[threadIdx.x - d] : 0u;
        __syncthreads();
        sT[threadIdx.x] += add;
        __syncthreads();
    }
    unsigned int excl = (threadIdx.x == 0) ? 0u : sT[threadIdx.x - 1];
    if (base     < n) out[base]     = excl;
    if (base + 1 < n) out[base + 1] = excl + v0;
    if (base + 2 < n) out[base + 2] = excl + v0 + v1;
    if (base + 3 < n) out[base + 3] = excl + v0 + v1 + v2;
    if (threadIdx.x == 255 && bsum) bsum[blockIdx.x] = sT[255];
}

__global__ __launch_bounds__(256) void k_scan_add(unsigned int* __restrict__ data,
                                                  const unsigned int* __restrict__ bscan,
                                                  int n) {
    int base = blockIdx.x * 1024 + threadIdx.x * 4;
    unsigned int add = bscan[blockIdx.x];
    if (base + 3 < n) {
        uint4 u = *(const uint4*)(data + base);
        u.x += add; u.y += add; u.z += add; u.w += add;
        *(uint4*)(data + base) = u;
    } else {
        if (base     < n) data[base]     += add;
        if (base + 1 < n) data[base + 1] += add;
        if (base + 2 < n) data[base + 2] += add;
        if (base + 3 < n) data[base + 3] += add;
    }
}

// ---------------- var embedding, prescaled by rsqrt(deg) ----------------
__global__ __launch_bounds__(256) void k_xvar(const float* __restrict__ var_c,
                                              const float* __restrict__ var_x,
                                              const unsigned int* __restrict__ deg_var,
                                              const float* __restrict__ Wv,
                                              const float* __restrict__ bv,
                                              float* __restrict__ Xs, int n) {
    int i = blockIdx.x * blockDim.x + threadIdx.x;
    if (i >= n) return;
    float c = var_c[i], x = var_x[i];
    float rs = rsqrtf(fmaxf((float)deg_var[i], 1.0f));
    float o[HFE];
#pragma unroll
    for (int j = 0; j < HFE; j++) {
        float t = fmaf(c, Wv[j], fmaf(x, Wv[HFE + j], bv[j]));
        o[j] = fmaxf(t, 0.0f) * rs;
    }
    float2* dst2 = (float2*)(Xs + (size_t)i * HFE);
#pragma unroll
    for (int j = 0; j < 5; j++) dst2[j] = make_float2(o[2 * j], o[2 * j + 1]);
}

// ---------------- CSR fill: csr[atomic(cursor[key])] = {val, w} ----------------
__global__ __launch_bounds__(256) void k_fill(const int* __restrict__ key,
                                              const int* __restrict__ val,
                                              const float* __restrict__ w,
                                              unsigned int* __restrict__ cursor,
                                              int2* __restrict__ csr, int ne) {
    int e = blockIdx.x * blockDim.x + threadIdx.x;
    if (e >= ne) return;
    unsigned int p = atomicAdd(&cursor[key[e]], 1u);
    csr[p] = make_int2(val[e], __float_as_int(w[e]));
}

// ---------------- conv1 gather: con nodes ----------------
__global__ __launch_bounds__(256) void k_gather_con(const int2* __restrict__ csr,
                                                    const unsigned int* __restrict__ cursor,
                                                    const unsigned int* __restrict__ deg,
                                                    const float* __restrict__ feat,
                                                    const float* __restrict__ W2,
                                                    const float* __restrict__ b2,
                                                    float* __restrict__ hs, int n) {
    __shared__ float sW[100], sb[10];
    for (int t = threadIdx.x; t < 100; t += blockDim.x) sW[t] = W2[t];
    if (threadIdx.x < 10) sb[threadIdx.x] = b2[threadIdx.x];
    __syncthreads();
    int i = blockIdx.x * blockDim.x + threadIdx.x;
    if (i >= n) return;
    unsigned int end = cursor[i], cnt = deg[i], beg = end - cnt;
    float acc[HFE];
#pragma unroll
    for (int j = 0; j < HFE; j++) acc[j] = 0.0f;
    for (unsigned int p = beg; p < end; ++p) {
        int2 t = csr[p];
        float we = __int_as_float(t.y);
        const float2* row = (const float2*)(feat + (size_t)t.x * HFE);
#pragma unroll
        for (int j = 0; j < 5; j++) {
            float2 v = row[j];
            acc[2 * j]     = fmaf(we, v.x, acc[2 * j]);
            acc[2 * j + 1] = fmaf(we, v.y, acc[2 * j + 1]);
        }
    }
    float rs = rsqrtf(fmaxf((float)cnt, 1.0f));
#pragma unroll
    for (int j = 0; j < HFE; j++) acc[j] *= rs;
    float o[HFE];
#pragma unroll
    for (int k = 0; k < HFE; k++) {
        float t = sb[k];
#pragma unroll
        for (int j = 0; j < HFE; j++) t = fmaf(acc[j], sW[j * HFE + k], t);
        o[k] = fmaxf(t, 0.0f) * rs;   // relu, then prescale for conv2
    }
    float2* dst2 = (float2*)(hs + (size_t)i * HFE);
#pragma unroll
    for (int j = 0; j < 5; j++) dst2[j] = make_float2(o[2 * j], o[2 * j + 1]);
}

// ---------------- conv2 gather + dense + MLP + partial mean ----------------
__global__ __launch_bounds__(256) void k_gather_final(const int2* __restrict__ csr,
                                                      const unsigned int* __restrict__ cursor,
                                                      const unsigned int* __restrict__ deg,
                                                      const float* __restrict__ feat,
                                                      const float* __restrict__ W2,
                                                      const float* __restrict__ b2,
                                                      const float* __restrict__ Wo1,
                                                      const float* __restrict__ bo1,
                                                      const float* __restrict__ Wo2,
                                                      const float* __restrict__ bo2,
                                                      const float* __restrict__ Wo3,
                                                      const float* __restrict__ bo3,
                                                      double* __restrict__ partials, int n) {
    __shared__ float sW2[100], sb2[10], sWo1[100], sbo1[10], sWo2[100], sbo2[10], sWo3[10], sbo3;
    for (int t = threadIdx.x; t < 100; t += blockDim.x) {
        sW2[t] = W2[t]; sWo1[t] = Wo1[t]; sWo2[t] = Wo2[t];
    }
    if (threadIdx.x < 10) {
        sb2[threadIdx.x]  = b2[threadIdx.x];
        sbo1[threadIdx.x] = bo1[threadIdx.x];
        sbo2[threadIdx.x] = bo2[threadIdx.x];
        sWo3[threadIdx.x] = Wo3[threadIdx.x];
    }
    if (threadIdx.x == 0) sbo3 = bo3[0];
    __syncthreads();

    double accd = 0.0;
    int i = blockIdx.x * blockDim.x + threadIdx.x;
    if (i < n) {
        unsigned int end = cursor[i], cnt = deg[i], beg = end - cnt;
        float acc[HFE];
#pragma unroll
        for (int j = 0; j < HFE; j++) acc[j] = 0.0f;
        for (unsigned int p = beg; p < end; ++p) {
            int2 t = csr[p];
            float we = __int_as_float(t.y);
            const float2* row = (const float2*)(feat + (size_t)t.x * HFE);
#pragma unroll
            for (int j = 0; j < 5; j++) {
                float2 v = row[j];
                acc[2 * j]     = fmaf(we, v.x, acc[2 * j]);
                acc[2 * j + 1] = fmaf(we, v.y, acc[2 * j + 1]);
            }
        }
        float rs = rsqrtf(fmaxf((float)cnt, 1.0f));
#pragma unroll
        for (int j = 0; j < HFE; j++) acc[j] *= rs;
        float h[HFE], z[HFE];
#pragma unroll
        for (int k = 0; k < HFE; k++) {
            float t = sb2[k];
#pragma unroll
            for (int j = 0; j < HFE; j++) t = fmaf(acc[j], sW2[j * HFE + k], t);
            h[k] = fmaxf(t, 0.0f);
        }
#pragma unroll
        for (int k = 0; k < HFE; k++) {
            float t = sbo1[k];
#pragma unroll
            for (int j = 0; j < HFE; j++) t = fmaf(h[j], sWo1[j * HFE + k], t);
            z[k] = fmaxf(t, 0.0f);
        }
        float t3 = sbo3;
#pragma unroll
        for (int k = 0; k < HFE; k++) {
            float t = sbo2[k];
#pragma unroll
            for (int j = 0; j < HFE; j++) t = fmaf(z[j], sWo2[j * HFE + k], t);
            t = fmaxf(t, 0.0f);
            t3 = fmaf(t, sWo3[k], t3);
        }
        accd = (double)t3;
    }

    __shared__ double red[256];
    red[threadIdx.x] = accd;
    __syncthreads();
    for (int off = blockDim.x / 2; off > 0; off >>= 1) {
        if (threadIdx.x < off) red[threadIdx.x] += red[threadIdx.x + off];
        __syncthreads();
    }
    if (threadIdx.x == 0) partials[blockIdx.x] = red[0];
}

__global__ __launch_bounds__(256) void k_out(const double* __restrict__ partials, int np,
                                             float* __restrict__ out) {
    __shared__ double red[256];
    double a = 0.0;
    for (int i = threadIdx.x; i < np; i += blockDim.x) a += partials[i];
    red[threadIdx.x] = a;
    __syncthreads();
    for (int off = 128; off > 0; off >>= 1) {
        if (threadIdx.x < off) red[threadIdx.x] += red[threadIdx.x + off];
        __syncthreads();
    }
    if (threadIdx.x == 0) out[0] = (float)(red[0] / (double)NVAR);
}

extern "C" void kernel_launch(void* const* d_in, const int* in_sizes, int n_in,
                              void* d_out, int out_size, void* d_ws, size_t ws_size,
                              hipStream_t stream) {
    const float* var_c  = (const float*)d_in[0];
    const float* var_x  = (const float*)d_in[1];
    const int*   e_src  = (const int*)d_in[3];
    const int*   e_dst  = (const int*)d_in[4];
    const float* e_w    = (const float*)d_in[5];
    const float* Wv     = (const float*)d_in[6];
    const float* bv     = (const float*)d_in[7];
    const float* W2     = (const float*)d_in[12];
    const float* b2     = (const float*)d_in[13];
    const float* Wo1    = (const float*)d_in[14];
    const float* bo1    = (const float*)d_in[15];
    const float* Wo2    = (const float*)d_in[16];
    const float* bo2    = (const float*)d_in[17];
    const float* Wo3    = (const float*)d_in[18];
    const float* bo3    = (const float*)d_in[19];
    float* out = (float*)d_out;
    const int ne = in_sizes[3];
    (void)n_in; (void)out_size; (void)ws_size;

    // ---- workspace layout (bytes) ----
    // [0, 40MB)      Xs                  }  after k_gather_con these are dead;
    // [40MB, 104MB)  csrC (int2 x 8M)    }  csrV (64MB) overlays [0, 64MB)
    // [104MB,124MB)  hs_con
    // [124MB, ...)   deg_var(4MB) deg_con(2MB) curV(4MB) curC(2MB) bsums partials
    char* ws = (char*)d_ws;
    float*        Xs      = (float*)(ws + 0);
    int2*         csrC    = (int2*)(ws + 40000000ull);
    float*        hs_con  = (float*)(ws + 104000000ull);
    int2*         csrV    = (int2*)(ws + 0);                 // overlay (Xs+csrC dead)
    unsigned int* deg_var = (unsigned int*)(ws + 124000256ull);
    unsigned int* deg_con = (unsigned int*)(ws + 128000256ull);
    unsigned int* curV    = (unsigned int*)(ws + 130000384ull);
    unsigned int* curC    = (unsigned int*)(ws + 134000384ull);
    unsigned int* bsumV   = (unsigned int*)(ws + 136000512ull);   // 977
    unsigned int* bscanV  = (unsigned int*)(ws + 136008704ull);   // 977
    unsigned int* bsumC   = (unsigned int*)(ws + 136016896ull);   // 489
    unsigned int* bscanC  = (unsigned int*)(ws + 136021248ull);   // 489
    unsigned int* bdummy  = (unsigned int*)(ws + 136025344ull);
    double*       partials= (double*)(ws + 136026112ull);         // 3907 doubles

    const int B = 256;
    const int NBV = (NVAR + 1023) / 1024;   // 977
    const int NBC = (NCON + 1023) / 1024;   // 489
    const int NF  = (NVAR + B - 1) / B;     // 3907

    // zero degree histograms (adjacent regions)
    hipMemsetAsync(deg_var, 0, (size_t)NVAR * 4 + (size_t)NCON * 4 + 512, stream);

    // 1. degrees
    k_degree<<<(ne + B - 1) / B, B, 0, stream>>>(e_src, e_dst, deg_var, deg_con, ne);

    // 2. exclusive scans -> cursors
    k_scan_blocks<<<NBV, B, 0, stream>>>(deg_var, curV, bsumV, NVAR);
    k_scan_blocks<<<1,   B, 0, stream>>>(bsumV, bscanV, bdummy, NBV);
    k_scan_add   <<<NBV, B, 0, stream>>>(curV, bscanV, NVAR);
    k_scan_blocks<<<NBC, B, 0, stream>>>(deg_con, curC, bsumC, NCON);
    k_scan_blocks<<<1,   B, 0, stream>>>(bsumC, bscanC, bdummy, NBC);
    k_scan_add   <<<NBC, B, 0, stream>>>(curC, bscanC, NCON);

    // 3. var embedding (prescaled)
    k_xvar<<<(NVAR + B - 1) / B, B, 0, stream>>>(var_c, var_x, deg_var, Wv, bv, Xs, NVAR);

    // 4. conv1: CSR by con, then gather
    k_fill<<<(ne + B - 1) / B, B, 0, stream>>>(e_dst, e_src, e_w, curC, csrC, ne);
    k_gather_con<<<(NCON + B - 1) / B, B, 0, stream>>>(csrC, curC, deg_con, Xs, W2, b2,
                                                       hs_con, NCON);

    // 5. conv2: CSR by var (overlays Xs/csrC), then gather + MLP + partial mean
    k_fill<<<(ne + B - 1) / B, B, 0, stream>>>(e_src, e_dst, e_w, curV, csrV, ne);
    k_gather_final<<<NF, B, 0, stream>>>(csrV, curV, deg_var, hs_con, W2, b2,
                                         Wo1, bo1, Wo2, bo2, Wo3, bo3, partials, NVAR);

    // 6. final mean
    k_out<<<1, B, 0, stream>>>(partials, NF, out);
}

// Round 3
// 1448.334 us; speedup vs baseline: 6.0173x; 1.6949x over previous
//
#include <hip/hip_runtime.h>

#define NVAR 1000000
#define NCON 500000
#define HFE 10

// ---------------- degree count + per-edge rank (returning int atomics) ----------------
__global__ __launch_bounds__(256) void k_degree_rank(const int4* __restrict__ src4,
                                                     const int4* __restrict__ dst4,
                                                     uchar4* __restrict__ rkS,
                                                     uchar4* __restrict__ rkD,
                                                     unsigned int* __restrict__ deg_var,
                                                     unsigned int* __restrict__ deg_con,
                                                     int ne4) {
    int t = blockIdx.x * blockDim.x + threadIdx.x;
    if (t >= ne4) return;
    int4 s = src4[t];
    int4 d = dst4[t];
    unsigned int r0 = atomicAdd(&deg_var[s.x], 1u);
    unsigned int r1 = atomicAdd(&deg_var[s.y], 1u);
    unsigned int r2 = atomicAdd(&deg_var[s.z], 1u);
    unsigned int r3 = atomicAdd(&deg_var[s.w], 1u);
    unsigned int q0 = atomicAdd(&deg_con[d.x], 1u);
    unsigned int q1 = atomicAdd(&deg_con[d.y], 1u);
    unsigned int q2 = atomicAdd(&deg_con[d.z], 1u);
    unsigned int q3 = atomicAdd(&deg_con[d.w], 1u);
    rkS[t] = make_uchar4((unsigned char)r0, (unsigned char)r1, (unsigned char)r2, (unsigned char)r3);
    rkD[t] = make_uchar4((unsigned char)q0, (unsigned char)q1, (unsigned char)q2, (unsigned char)q3);
}

// ---------------- exclusive scan, 1024 elements / block ----------------
__global__ __launch_bounds__(256) void k_scan_blocks(const unsigned int* __restrict__ in,
                                                     unsigned int* __restrict__ out,
                                                     unsigned int* __restrict__ bsum,
                                                     int n) {
    __shared__ unsigned int sT[256];
    int base = blockIdx.x * 1024 + threadIdx.x * 4;
    unsigned int v0 = 0, v1 = 0, v2 = 0, v3 = 0;
    if (base + 3 < n) {
        uint4 u = *(const uint4*)(in + base);
        v0 = u.x; v1 = u.y; v2 = u.z; v3 = u.w;
    } else {
        if (base     < n) v0 = in[base];
        if (base + 1 < n) v1 = in[base + 1];
        if (base + 2 < n) v2 = in[base + 2];
        if (base + 3 < n) v3 = in[base + 3];
    }
    sT[threadIdx.x] = v0 + v1 + v2 + v3;
    __syncthreads();
    for (int d = 1; d < 256; d <<= 1) {
        unsigned int add = (threadIdx.x >= (unsigned)d) ? sT[threadIdx.x - d] : 0u;
        __syncthreads();
        sT[threadIdx.x] += add;
        __syncthreads();
    }
    unsigned int excl = (threadIdx.x == 0) ? 0u : sT[threadIdx.x - 1];
    if (base     < n) out[base]     = excl;
    if (base + 1 < n) out[base + 1] = excl + v0;
    if (base + 2 < n) out[base + 2] = excl + v0 + v1;
    if (base + 3 < n) out[base + 3] = excl + v0 + v1 + v2;
    if (threadIdx.x == 255 && bsum) bsum[blockIdx.x] = sT[255];
}

__global__ __launch_bounds__(256) void k_scan_add(unsigned int* __restrict__ data,
                                                  const unsigned int* __restrict__ bscan,
                                                  int n) {
    int base = blockIdx.x * 1024 + threadIdx.x * 4;
    unsigned int add = bscan[blockIdx.x];
    if (base + 3 < n) {
        uint4 u = *(const uint4*)(data + base);
        u.x += add; u.y += add; u.z += add; u.w += add;
        *(uint4*)(data + base) = u;
    } else {
        if (base     < n) data[base]     += add;
        if (base + 1 < n) data[base + 1] += add;
        if (base + 2 < n) data[base + 2] += add;
        if (base + 3 < n) data[base + 3] += add;
    }
}

// ---------------- var embedding, prescaled by rsqrt(deg) ----------------
__global__ __launch_bounds__(256) void k_xvar(const float* __restrict__ var_c,
                                              const float* __restrict__ var_x,
                                              const unsigned int* __restrict__ deg_var,
                                              const float* __restrict__ Wv,
                                              const float* __restrict__ bv,
                                              float* __restrict__ Xs, int n) {
    int i = blockIdx.x * blockDim.x + threadIdx.x;
    if (i >= n) return;
    float c = var_c[i], x = var_x[i];
    float rs = rsqrtf(fmaxf((float)deg_var[i], 1.0f));
    float o[HFE];
#pragma unroll
    for (int j = 0; j < HFE; j++) {
        float t = fmaf(c, Wv[j], fmaf(x, Wv[HFE + j], bv[j]));
        o[j] = fmaxf(t, 0.0f) * rs;
    }
    float2* dst2 = (float2*)(Xs + (size_t)i * HFE);
#pragma unroll
    for (int j = 0; j < 5; j++) dst2[j] = make_float2(o[2 * j], o[2 * j + 1]);
}

// ---------------- CSR fill, atomic-free: csr[cur[key]+rank] = {val, w} ----------------
__global__ __launch_bounds__(256) void k_fill(const int4* __restrict__ key4,
                                              const int4* __restrict__ val4,
                                              const float4* __restrict__ w4,
                                              const uchar4* __restrict__ rk4,
                                              const unsigned int* __restrict__ cur,
                                              int2* __restrict__ csr, int ne4) {
    int t = blockIdx.x * blockDim.x + threadIdx.x;
    if (t >= ne4) return;
    int4 k = key4[t];
    int4 v = val4[t];
    float4 w = w4[t];
    uchar4 r = rk4[t];
    unsigned int p0 = cur[k.x] + r.x;
    unsigned int p1 = cur[k.y] + r.y;
    unsigned int p2 = cur[k.z] + r.z;
    unsigned int p3 = cur[k.w] + r.w;
    csr[p0] = make_int2(v.x, __float_as_int(w.x));
    csr[p1] = make_int2(v.y, __float_as_int(w.y));
    csr[p2] = make_int2(v.z, __float_as_int(w.z));
    csr[p3] = make_int2(v.w, __float_as_int(w.w));
}

// ---------------- conv1 gather: con nodes ----------------
__global__ __launch_bounds__(256) void k_gather_con(const int2* __restrict__ csr,
                                                    const unsigned int* __restrict__ start,
                                                    const unsigned int* __restrict__ deg,
                                                    const float* __restrict__ feat,
                                                    const float* __restrict__ W2,
                                                    const float* __restrict__ b2,
                                                    float* __restrict__ hs, int n) {
    __shared__ float sW[100], sb[10];
    for (int t = threadIdx.x; t < 100; t += blockDim.x) sW[t] = W2[t];
    if (threadIdx.x < 10) sb[threadIdx.x] = b2[threadIdx.x];
    __syncthreads();
    int i = blockIdx.x * blockDim.x + threadIdx.x;
    if (i >= n) return;
    unsigned int beg = start[i], cnt = deg[i], end = beg + cnt;
    float acc[HFE];
#pragma unroll
    for (int j = 0; j < HFE; j++) acc[j] = 0.0f;
    for (unsigned int p = beg; p < end; ++p) {
        int2 t = csr[p];
        float we = __int_as_float(t.y);
        const float2* row = (const float2*)(feat + (size_t)t.x * HFE);
#pragma unroll
        for (int j = 0; j < 5; j++) {
            float2 v = row[j];
            acc[2 * j]     = fmaf(we, v.x, acc[2 * j]);
            acc[2 * j + 1] = fmaf(we, v.y, acc[2 * j + 1]);
        }
    }
    float rs = rsqrtf(fmaxf((float)cnt, 1.0f));
#pragma unroll
    for (int j = 0; j < HFE; j++) acc[j] *= rs;
    float o[HFE];
#pragma unroll
    for (int k = 0; k < HFE; k++) {
        float t = sb[k];
#pragma unroll
        for (int j = 0; j < HFE; j++) t = fmaf(acc[j], sW[j * HFE + k], t);
        o[k] = fmaxf(t, 0.0f) * rs;   // relu, then prescale for conv2
    }
    float2* dst2 = (float2*)(hs + (size_t)i * HFE);
#pragma unroll
    for (int j = 0; j < 5; j++) dst2[j] = make_float2(o[2 * j], o[2 * j + 1]);
}

// ---------------- conv2 gather + dense + MLP + partial mean ----------------
__global__ __launch_bounds__(256) void k_gather_final(const int2* __restrict__ csr,
                                                      const unsigned int* __restrict__ start,
                                                      const unsigned int* __restrict__ deg,
                                                      const float* __restrict__ feat,
                                                      const float* __restrict__ W2,
                                                      const float* __restrict__ b2,
                                                      const float* __restrict__ Wo1,
                                                      const float* __restrict__ bo1,
                                                      const float* __restrict__ Wo2,
                                                      const float* __restrict__ bo2,
                                                      const float* __restrict__ Wo3,
                                                      const float* __restrict__ bo3,
                                                      double* __restrict__ partials, int n) {
    __shared__ float sW2[100], sb2[10], sWo1[100], sbo1[10], sWo2[100], sbo2[10], sWo3[10], sbo3;
    for (int t = threadIdx.x; t < 100; t += blockDim.x) {
        sW2[t] = W2[t]; sWo1[t] = Wo1[t]; sWo2[t] = Wo2[t];
    }
    if (threadIdx.x < 10) {
        sb2[threadIdx.x]  = b2[threadIdx.x];
        sbo1[threadIdx.x] = bo1[threadIdx.x];
        sbo2[threadIdx.x] = bo2[threadIdx.x];
        sWo3[threadIdx.x] = Wo3[threadIdx.x];
    }
    if (threadIdx.x == 0) sbo3 = bo3[0];
    __syncthreads();

    double accd = 0.0;
    int i = blockIdx.x * blockDim.x + threadIdx.x;
    if (i < n) {
        unsigned int beg = start[i], cnt = deg[i], end = beg + cnt;
        float acc[HFE];
#pragma unroll
        for (int j = 0; j < HFE; j++) acc[j] = 0.0f;
        for (unsigned int p = beg; p < end; ++p) {
            int2 t = csr[p];
            float we = __int_as_float(t.y);
            const float2* row = (const float2*)(feat + (size_t)t.x * HFE);
#pragma unroll
            for (int j = 0; j < 5; j++) {
                float2 v = row[j];
                acc[2 * j]     = fmaf(we, v.x, acc[2 * j]);
                acc[2 * j + 1] = fmaf(we, v.y, acc[2 * j + 1]);
            }
        }
        float rs = rsqrtf(fmaxf((float)cnt, 1.0f));
#pragma unroll
        for (int j = 0; j < HFE; j++) acc[j] *= rs;
        float h[HFE], z[HFE];
#pragma unroll
        for (int k = 0; k < HFE; k++) {
            float t = sb2[k];
#pragma unroll
            for (int j = 0; j < HFE; j++) t = fmaf(acc[j], sW2[j * HFE + k], t);
            h[k] = fmaxf(t, 0.0f);
        }
#pragma unroll
        for (int k = 0; k < HFE; k++) {
            float t = sbo1[k];
#pragma unroll
            for (int j = 0; j < HFE; j++) t = fmaf(h[j], sWo1[j * HFE + k], t);
            z[k] = fmaxf(t, 0.0f);
        }
        float t3 = sbo3;
#pragma unroll
        for (int k = 0; k < HFE; k++) {
            float t = sbo2[k];
#pragma unroll
            for (int j = 0; j < HFE; j++) t = fmaf(z[j], sWo2[j * HFE + k], t);
            t = fmaxf(t, 0.0f);
            t3 = fmaf(t, sWo3[k], t3);
        }
        accd = (double)t3;
    }

    __shared__ double red[256];
    red[threadIdx.x] = accd;
    __syncthreads();
    for (int off = blockDim.x / 2; off > 0; off >>= 1) {
        if (threadIdx.x < off) red[threadIdx.x] += red[threadIdx.x + off];
        __syncthreads();
    }
    if (threadIdx.x == 0) partials[blockIdx.x] = red[0];
}

__global__ __launch_bounds__(256) void k_out(const double* __restrict__ partials, int np,
                                             float* __restrict__ out) {
    __shared__ double red[256];
    double a = 0.0;
    for (int i = threadIdx.x; i < np; i += blockDim.x) a += partials[i];
    red[threadIdx.x] = a;
    __syncthreads();
    for (int off = 128; off > 0; off >>= 1) {
        if (threadIdx.x < off) red[threadIdx.x] += red[threadIdx.x + off];
        __syncthreads();
    }
    if (threadIdx.x == 0) out[0] = (float)(red[0] / (double)NVAR);
}

extern "C" void kernel_launch(void* const* d_in, const int* in_sizes, int n_in,
                              void* d_out, int out_size, void* d_ws, size_t ws_size,
                              hipStream_t stream) {
    const float* var_c  = (const float*)d_in[0];
    const float* var_x  = (const float*)d_in[1];
    const int*   e_src  = (const int*)d_in[3];
    const int*   e_dst  = (const int*)d_in[4];
    const float* e_w    = (const float*)d_in[5];
    const float* Wv     = (const float*)d_in[6];
    const float* bv     = (const float*)d_in[7];
    const float* W2     = (const float*)d_in[12];
    const float* b2     = (const float*)d_in[13];
    const float* Wo1    = (const float*)d_in[14];
    const float* bo1    = (const float*)d_in[15];
    const float* Wo2    = (const float*)d_in[16];
    const float* bo2    = (const float*)d_in[17];
    const float* Wo3    = (const float*)d_in[18];
    const float* bo3    = (const float*)d_in[19];
    float* out = (float*)d_out;
    const int ne = in_sizes[3];
    (void)n_in; (void)out_size; (void)ws_size;

    // ---- workspace layout (256B-aligned bump allocator) ----
    char* ws = (char*)d_ws;
    size_t off = 0;
    auto walloc = [&](size_t bytes) {
        void* p = ws + off;
        off = (off + bytes + 255) & ~(size_t)255;
        return p;
    };
    float*        Xs      = (float*)walloc((size_t)NVAR * HFE * 4);   // 40 MB
    int2*         csrC    = (int2*)walloc((size_t)8000000 * 8);       // 64 MB
    float*        hs_con  = (float*)walloc((size_t)NCON * HFE * 4);   // 20 MB
    uchar4*       rkS     = (uchar4*)walloc((size_t)8000000);         //  8 MB
    uchar4*       rkD     = (uchar4*)walloc((size_t)8000000);         //  8 MB
    unsigned int* deg_var = (unsigned int*)walloc((size_t)NVAR * 4);  //  4 MB
    unsigned int* deg_con = (unsigned int*)walloc((size_t)NCON * 4);  //  2 MB
    unsigned int* curV    = (unsigned int*)walloc((size_t)NVAR * 4);  //  4 MB
    unsigned int* curC    = (unsigned int*)walloc((size_t)NCON * 4);  //  2 MB
    unsigned int* bsumV   = (unsigned int*)walloc(4096);
    unsigned int* bscanV  = (unsigned int*)walloc(4096);
    unsigned int* bsumC   = (unsigned int*)walloc(4096);
    unsigned int* bscanC  = (unsigned int*)walloc(4096);
    unsigned int* bdummy  = (unsigned int*)walloc(256);
    double*       partials= (double*)walloc(3908 * 8);
    // csrV overlays [Xs, csrC-head): both dead after k_gather_con
    int2*         csrV    = (int2*)(ws + 0);                          // 64 MB overlay

    const int B = 256;
    const int NBV = (NVAR + 1023) / 1024;   // 977
    const int NBC = (NCON + 1023) / 1024;   // 489
    const int NF  = (NVAR + B - 1) / B;     // 3907
    const int ne4 = ne / 4;                 // ne = 8M, divisible by 4

    // zero degree histograms (deg_var and deg_con are contiguous)
    hipMemsetAsync(deg_var, 0, (size_t)NVAR * 4 + (size_t)NCON * 4, stream);

    // 1. degrees + per-edge ranks (the only atomics in the pipeline)
    k_degree_rank<<<(ne4 + B - 1) / B, B, 0, stream>>>(
        (const int4*)e_src, (const int4*)e_dst, rkS, rkD, deg_var, deg_con, ne4);

    // 2. exclusive scans -> segment starts
    k_scan_blocks<<<NBV, B, 0, stream>>>(deg_var, curV, bsumV, NVAR);
    k_scan_blocks<<<1,   B, 0, stream>>>(bsumV, bscanV, bdummy, NBV);
    k_scan_add   <<<NBV, B, 0, stream>>>(curV, bscanV, NVAR);
    k_scan_blocks<<<NBC, B, 0, stream>>>(deg_con, curC, bsumC, NCON);
    k_scan_blocks<<<1,   B, 0, stream>>>(bsumC, bscanC, bdummy, NBC);
    k_scan_add   <<<NBC, B, 0, stream>>>(curC, bscanC, NCON);

    // 3. var embedding (prescaled)
    k_xvar<<<(NVAR + B - 1) / B, B, 0, stream>>>(var_c, var_x, deg_var, Wv, bv, Xs, NVAR);

    // 4. conv1: atomic-free CSR fill by con, then gather
    k_fill<<<(ne4 + B - 1) / B, B, 0, stream>>>(
        (const int4*)e_dst, (const int4*)e_src, (const float4*)e_w, rkD, curC, csrC, ne4);
    k_gather_con<<<(NCON + B - 1) / B, B, 0, stream>>>(csrC, curC, deg_con, Xs, W2, b2,
                                                       hs_con, NCON);

    // 5. conv2: atomic-free CSR fill by var (csrV overlays dead Xs/csrC-head)
    k_fill<<<(ne4 + B - 1) / B, B, 0, stream>>>(
        (const int4*)e_src, (const int4*)e_dst, (const float4*)e_w, rkS, curV, csrV, ne4);
    k_gather_final<<<NF, B, 0, stream>>>(csrV, curV, deg_var, hs_con, W2, b2,
                                         Wo1, bo1, Wo2, bo2, Wo3, bo3, partials, NVAR);

    // 6. final mean
    k_out<<<1, B, 0, stream>>>(partials, NF, out);
}